// Round 21
// baseline (168.234 us; speedup 1.0000x reference)
//
#include <hip/hip_runtime.h>
#include <hip/hip_bf16.h>
#include <cstdint>
#include <cstddef>

// Problem constants: B=32, N=768, D=768
#define BN_ROWS 24576
#define DD 768
#define BE (768*768)
#define BM 192
#define BN_T 192
#define BK 32
#define ABUF 12288
#define BUFSZ 24576

typedef __attribute__((ext_vector_type(8))) short bf16x8;
typedef __attribute__((ext_vector_type(4))) float f32x4;
typedef __attribute__((ext_vector_type(8))) unsigned short u16x8;

static __device__ __forceinline__ unsigned short f2bf(float f) {
  unsigned int u = __builtin_bit_cast(unsigned int, f);
  unsigned int lsb = (u >> 16) & 1u;
  u += 0x7fffu + lsb;
  return (unsigned short)(u >> 16);
}
static __device__ __forceinline__ unsigned short f2bfv(float f) {
  __hip_bfloat16 h = __float2bfloat16(f);
  return __builtin_bit_cast(unsigned short, h);
}
static __device__ __forceinline__ bf16x8 cvt8(float4 u, float4 w) {
  bf16x8 o;
  o[0] = (short)f2bfv(u.x); o[1] = (short)f2bfv(u.y);
  o[2] = (short)f2bfv(u.z); o[3] = (short)f2bfv(u.w);
  o[4] = (short)f2bfv(w.x); o[5] = (short)f2bfv(w.y);
  o[6] = (short)f2bfv(w.z); o[7] = (short)f2bfv(w.w);
  return o;
}
static __device__ __forceinline__ u16x8 pack8s(float4 a, float4 b, float sc) {
  u16x8 o;
  o[0] = f2bfv(a.x * sc); o[1] = f2bfv(a.y * sc);
  o[2] = f2bfv(a.z * sc); o[3] = f2bfv(a.w * sc);
  o[4] = f2bfv(b.x * sc); o[5] = f2bfv(b.y * sc);
  o[6] = f2bfv(b.z * sc); o[7] = f2bfv(b.w * sc);
  return o;
}

// Frag-linear layout for a 768(col) x 768(k) bf16 B-matrix:
//   block f = (col>>4)*24 + (k>>5); elem = f*512 + ((col&15)+(((k>>3)&3)<<4))*8 + (k&7)

// ---------------- prep: adjNorm (bf16, 16B stores) + both weights row-major ----------------
#define P_AN 3072
#define P_WT 144

__global__ __launch_bounds__(256) void prep(const float* __restrict__ adj,
                                            const float* __restrict__ Wl,
                                            const float* __restrict__ Wl1,
                                            unsigned short* __restrict__ adjnb,
                                            unsigned short* __restrict__ WlT,
                                            unsigned short* __restrict__ Wl1T) {
  __shared__ float tile[64][65];
  const int bid = blockIdx.x;
  if (bid < P_AN) {
    const int w = threadIdx.x >> 6;
    const int hl = (threadIdx.x >> 5) & 1;
    const int l = threadIdx.x & 31;
    const int row = bid * 8 + w * 2 + hl;
    const float4* a = reinterpret_cast<const float4*>(adj + (size_t)row * DD);
    float4 v[6];
    #pragma unroll
    for (int i = 0; i < 3; ++i) {
      int u = l + i * 32;
      v[2 * i]     = a[u * 2];
      v[2 * i + 1] = a[u * 2 + 1];
    }
    float s = 0.f;
    #pragma unroll
    for (int i = 0; i < 6; ++i) s += (v[i].x + v[i].y) + (v[i].z + v[i].w);
    #pragma unroll
    for (int off = 16; off; off >>= 1) s += __shfl_xor(s, off);
    float rinv = (s == 0.f) ? 0.f : 1.f / s;
    u16x8* o = reinterpret_cast<u16x8*>(adjnb + (size_t)row * DD);
    #pragma unroll
    for (int i = 0; i < 3; ++i)
      o[l + i * 32] = pack8s(v[2 * i], v[2 * i + 1], rinv);
  } else {
    const int tb = bid - P_AN;
    const int tr = tb / 12, tc = tb % 12;
    const int c = threadIdx.x & 63, r0 = threadIdx.x >> 6;
    const float* srcs[2] = {Wl, Wl1};
    unsigned short* dsts[2] = {WlT, Wl1T};
    #pragma unroll
    for (int m = 0; m < 2; ++m) {
      const float* src = srcs[m];
      #pragma unroll
      for (int i = 0; i < 16; ++i) {
        int r = r0 + i * 4;
        tile[r][c] = src[(size_t)(tr * 64 + r) * DD + tc * 64 + c];
      }
      __syncthreads();
      unsigned short* dst = dsts[m];
      #pragma unroll
      for (int i = 0; i < 16; ++i) {
        int r2 = r0 + i * 4;
        dst[(size_t)(tc * 64 + r2) * DD + tr * 64 + c] = f2bf(tile[c][r2]);
      }
      __syncthreads();
    }
  }
}

// ===== shared GEMM machinery (R14/R20-proven): 192x192, A = fp32 reg-staged,
// B via gload_lds from row-major. Counted schedule: vmcnt(6)/vmcnt(3), never 0
// in loop. MODE selects B source + epilogue: 0 -> e1T frag-linear; 1 -> X1f
// bg-matched [flatblk][elem][tid] layout (verified R17). =====

template<int MODE>
__global__ __launch_bounds__(256, 2) void gemm_xw(
    const float* __restrict__ X,
    const unsigned short* __restrict__ Brow,    // row-major weight transpose
    unsigned short* __restrict__ outT)          // MODE0: e1T  MODE1: X1f
{
  __shared__ char smem[2 * BUFSZ];
  constexpr int NT = 24;
  const int tid = threadIdx.x, lane = tid & 63;
  const int wid = tid >> 6;
  const int wr = wid >> 1, wc = wid & 1;

  const int logical = (blockIdx.x & 7) * 64 + (blockIdx.x >> 3);
  const int mt = logical >> 2, nt = logical & 3;
  const int b = mt >> 2;
  const float* Ag = X + (size_t)mt * BM * DD;
  const unsigned short* Bg = Brow + (size_t)nt * BN_T * DD;

  const int r_in = lane >> 2;
  const int s_in = lane & 3;

  float4 aR[3][2];
  auto issueA = [&](int s) {
    int kk = s < NT ? s : 0;
    #pragma unroll
    for (int i = 0; i < 3; ++i) {
      int row = (wid * 3 + i) * 16 + r_in;
      int slot = s_in ^ ((row >> 1) & 3);
      const float4* p = reinterpret_cast<const float4*>(
          Ag + (size_t)row * DD + kk * BK + slot * 8);
      aR[i][0] = p[0];
      aR[i][1] = p[1];
    }
  };
  auto writeA = [&](int s) {
    const int buf = (s & 1) * BUFSZ;
    #pragma unroll
    for (int i = 0; i < 3; ++i)
      *reinterpret_cast<bf16x8*>(smem + buf + (wid * 3 + i) * 1024 + lane * 16) =
          cvt8(aR[i][0], aR[i][1]);
  };
  auto issueB = [&](int s) {
    int kk = s < NT ? s : 0;
    const int buf = (s & 1) * BUFSZ + ABUF;
    #pragma unroll
    for (int i = 0; i < 3; ++i) {
      int c = wid * 3 + i;
      int row = c * 16 + r_in;
      int slot = s_in ^ ((row >> 1) & 3);
      const unsigned short* src = Bg + (size_t)row * DD + kk * BK + slot * 8;
      __builtin_amdgcn_global_load_lds(
          (const __attribute__((address_space(1))) void*)src,
          (__attribute__((address_space(3))) void*)(smem + buf + c * 1024),
          16, 0, 0);
    }
  };

  const int ks = lane >> 4;
  auto frag = [&](int off, int row) -> bf16x8 {
    int slot = ks ^ ((row >> 1) & 3);
    return *reinterpret_cast<const bf16x8*>(smem + off + row * 64 + slot * 16);
  };

  f32x4 acc[6][6] = {};
  const int arow = wr * 96 + (lane & 15);
  const int brow = wc * 96 + (lane & 15);

  // prologue: in-flight at loop entry = B(0)[3, oldest] + A(1)[6]
  issueA(0);
  asm volatile("s_waitcnt vmcnt(0)" ::: "memory");
  writeA(0);
  issueB(0);
  issueA(1);
  asm volatile("s_waitcnt lgkmcnt(0)" ::: "memory");
  __builtin_amdgcn_s_barrier();

  for (int t = 0; t < NT; ++t) {
    asm volatile("s_waitcnt vmcnt(6)" ::: "memory");   // retire B(t); A(t+1) stays
    __builtin_amdgcn_s_barrier();
    issueB(t + 1);                                     // -> buf[(t+1)&1].B (safe)

    const int bufA = (t & 1) * BUFSZ;
    const int bufB = bufA + ABUF;
    bf16x8 a[6], bg[6];
    #pragma unroll
    for (int i = 0; i < 6; ++i) a[i] = frag(bufA, arow + i * 16);
    #pragma unroll
    for (int i = 0; i < 6; ++i) bg[i] = frag(bufB, brow + i * 16);

    __builtin_amdgcn_s_setprio(1);
    #pragma unroll
    for (int ni = 0; ni < 6; ++ni)
      #pragma unroll
      for (int mi = 0; mi < 6; ++mi)
        acc[mi][ni] = __builtin_amdgcn_mfma_f32_16x16x32_bf16(a[mi], bg[ni], acc[mi][ni], 0, 0, 0);
    __builtin_amdgcn_s_setprio(0);

    asm volatile("s_waitcnt vmcnt(3)" ::: "memory");   // retire A-fp32(t+1)
    writeA(t + 1);                                     // -> buf[(t+1)&1].A (safe)
    issueA(t + 2);                                     // invariant restored
    asm volatile("s_waitcnt lgkmcnt(0)" ::: "memory"); // ds_writes visible pre-barrier
  }

  const int l15 = lane & 15;
  if (MODE == 0) {
    // frag-linear e1T (col=d, k=m)   [verified R13-R20]
    unsigned short* ob = outT + (size_t)b * BE;
    const int m0 = (mt & 3) * BM + wr * 96 + (lane >> 4) * 4;
    #pragma unroll
    for (int mi = 0; mi < 6; ++mi)
      #pragma unroll
      for (int ni = 0; ni < 6; ++ni) {
        int m = m0 + mi * 16;
        int cb = nt * 12 + wc * 6 + ni;
        int fa = (cb * 24 + (m >> 5)) * 512
               + (l15 + (((m >> 3) & 3) << 4)) * 8 + (m & 7);
        f32x4 v = acc[mi][ni];
        ushort4 o;
        o.x = f2bf(v[0]); o.y = f2bf(v[1]); o.z = f2bf(v[2]); o.w = f2bf(v[3]);
        *reinterpret_cast<ushort4*>(ob + fa) = o;
      }
  } else {
    // X1f bg-matched [flatblk][elem][tid] layout   [verified R17]
    const int flat = b * 16 + (mt & 3) * 4 + nt;
    ushort4* o4 = reinterpret_cast<ushort4*>(outT) + (size_t)flat * 36 * 256 + tid;
    #pragma unroll
    for (int mi = 0; mi < 6; ++mi)
      #pragma unroll
      for (int ni = 0; ni < 6; ++ni) {
        f32x4 v = acc[mi][ni];
        ushort4 o;
        o.x = f2bf(v[0]); o.y = f2bf(v[1]); o.z = f2bf(v[2]); o.w = f2bf(v[3]);
        o4[(mi * 6 + ni) * 256] = o;
      }
  }
}

// ----- gemm_bg24 (R17 verbatim): out = leaky( adjnb @ e1 + X1 ), 24 tiles -----
__global__ __launch_bounds__(256, 2) void gemm_bg(
    const unsigned short* __restrict__ adjnb,
    const unsigned short* __restrict__ e1T,
    const unsigned short* __restrict__ X1f,
    float* __restrict__ out)
{
  __shared__ char smem[24576];
  constexpr int NT = 24;
  const int tid = threadIdx.x, lane = tid & 63;
  const int wid = tid >> 6;
  const int wr = wid >> 1, wc = wid & 1;

  const int logical = (blockIdx.x & 7) * 64 + (blockIdx.x >> 3);   // 512 = 8x64
  const int b = logical >> 4;
  const int r = logical & 15;
  const int mt = r >> 2, nt = r & 3;
  const size_t bo = (size_t)b * BE;
  const unsigned short* A0 = adjnb + bo + (size_t)mt * BM * DD;
  const unsigned short* B0 = e1T + bo;

  const int r_in = lane >> 2;
  const int s_in = lane & 3;
  const int colblk0 = nt * 12 + wc * 6;

  auto stage = [&](int s) {
    int kk = s < NT ? s : 0;
    const int buf = (s & 1) * 12288;
    #pragma unroll
    for (int i = 0; i < 3; ++i) {
      int chunk = wid * 3 + i;
      int row = chunk * 16 + r_in;
      int slot = s_in ^ ((row >> 1) & 3);
      const unsigned short* src = A0 + (size_t)row * DD + kk * BK + slot * 8;
      __builtin_amdgcn_global_load_lds(
          (const __attribute__((address_space(1))) void*)src,
          (__attribute__((address_space(3))) void*)(smem + buf + chunk * 1024),
          16, 0, 0);
    }
  };
  auto loadB = [&](int s, bf16x8* dst) {
    int kk = s < NT ? s : 0;
    #pragma unroll
    for (int ni = 0; ni < 6; ++ni)
      dst[ni] = *reinterpret_cast<const bf16x8*>(
          B0 + ((colblk0 + ni) * 24 + kk) * 512 + lane * 8);
  };

  const int ks = lane >> 4;
  auto rdA = [&](int off, int row) -> bf16x8 {
    int slot = ks ^ ((row >> 1) & 3);
    return *reinterpret_cast<const bf16x8*>(smem + off + row * 64 + slot * 16);
  };

  f32x4 acc[6][6] = {};
  const int arow = wr * 96 + (lane & 15);
  bf16x8 bA[6], bB[6];

  auto body = [&](int bufo, bf16x8* bfr) {
    #pragma unroll
    for (int mh = 0; mh < 2; ++mh) {
      bf16x8 a[3];
      #pragma unroll
      for (int i = 0; i < 3; ++i) a[i] = rdA(bufo, arow + mh * 48 + i * 16);
      __builtin_amdgcn_s_setprio(1);
      #pragma unroll
      for (int mi = 0; mi < 3; ++mi)
        #pragma unroll
        for (int ni = 0; ni < 6; ++ni)
          acc[mh * 3 + mi][ni] = __builtin_amdgcn_mfma_f32_16x16x32_bf16(
              a[mi], bfr[ni], acc[mh * 3 + mi][ni], 0, 0, 0);
      __builtin_amdgcn_s_setprio(0);
    }
  };

  stage(0); loadB(0, bA);
  for (int t = 0; t < NT; t += 2) {
    asm volatile("s_waitcnt vmcnt(6)" ::: "memory");
    __builtin_amdgcn_s_barrier();
    stage(t + 1); loadB(t + 1, bB);
    body(0, bA);
    asm volatile("s_waitcnt vmcnt(6)" ::: "memory");
    __builtin_amdgcn_s_barrier();
    stage(t + 2); loadB(t + 2, bA);
    body(12288, bB);
  }
  asm volatile("s_waitcnt vmcnt(0)" ::: "memory");

  // epilogue: + X1 (matched layout), leaky, fp32 store
  float* ob = out + bo;
  const int m0 = mt * BM + wr * 96 + (lane >> 4) * 4;
  const int l15 = lane & 15;
  const int flat = b * 16 + mt * 4 + nt;
  const ushort4* x4 = reinterpret_cast<const ushort4*>(X1f) + (size_t)flat * 36 * 256 + tid;
  #pragma unroll
  for (int mi = 0; mi < 6; ++mi)
    #pragma unroll
    for (int ni = 0; ni < 6; ++ni) {
      int m = m0 + mi * 16;
      int n = nt * 192 + wc * 96 + ni * 16 + l15;
      ushort4 xi = x4[(mi * 6 + ni) * 256];
      f32x4 v = acc[mi][ni];
      float x1v[4];
      x1v[0] = __builtin_bit_cast(float, (unsigned int)xi.x << 16);
      x1v[1] = __builtin_bit_cast(float, (unsigned int)xi.y << 16);
      x1v[2] = __builtin_bit_cast(float, (unsigned int)xi.z << 16);
      x1v[3] = __builtin_bit_cast(float, (unsigned int)xi.w << 16);
      #pragma unroll
      for (int j = 0; j < 4; ++j) {
        float x = v[j] + x1v[j];
        ob[(size_t)(m + j) * DD + n] = x > 0.f ? x : 0.01f * x;
      }
    }
}

// ---------------- launch ----------------

extern "C" void kernel_launch(void* const* d_in, const int* in_sizes, int n_in,
                              void* d_out, int out_size, void* d_ws, size_t ws_size,
                              hipStream_t stream) {
  const float* X   = (const float*)d_in[0];
  const float* adj = (const float*)d_in[1];
  const float* Wl  = (const float*)d_in[2];
  const float* Wl1 = (const float*)d_in[3];
  float* out = (float*)d_out;

  char* ws = (char*)d_ws;
  const size_t SZ = (size_t)BN_ROWS * DD * 2;     // 37,748,736 bytes
  unsigned short* e1T   = (unsigned short*)(ws);                      // frag-linear
  unsigned short* adjnb = (unsigned short*)(ws + SZ);                 // row-major bf16
  unsigned short* X1f   = (unsigned short*)(ws + 2 * SZ);             // bg-matched layout
  unsigned short* WlT   = (unsigned short*)(ws + 3 * SZ);                  // row-major
  unsigned short* Wl1T  = (unsigned short*)(ws + 3 * SZ + (size_t)BE * 2); // row-major

  prep<<<P_AN + P_WT, 256, 0, stream>>>(adj, Wl, Wl1, adjnb, WlT, Wl1T);
  gemm_xw<0><<<512, 256, 0, stream>>>(X, Wl1T, e1T);
  gemm_xw<1><<<512, 256, 0, stream>>>(X, WlT, X1f);
  gemm_bg<<<512, 256, 0, stream>>>(adjnb, e1T, X1f, out);
}

// Round 22
// 152.125 us; speedup vs baseline: 1.1059x; 1.1059x over previous
//
#include <hip/hip_runtime.h>
#include <hip/hip_bf16.h>
#include <cstdint>
#include <cstddef>

// Problem constants: B=32, N=768, D=768
#define BN_ROWS 24576
#define DD 768
#define BE (768*768)
#define BM 192
#define BN_T 192
#define BK 32
#define ABUF 12288
#define BUFSZ 24576

typedef __attribute__((ext_vector_type(8))) short bf16x8;
typedef __attribute__((ext_vector_type(4))) float f32x4;
typedef __attribute__((ext_vector_type(8))) unsigned short u16x8;

static __device__ __forceinline__ unsigned short f2bf(float f) {
  unsigned int u = __builtin_bit_cast(unsigned int, f);
  unsigned int lsb = (u >> 16) & 1u;
  u += 0x7fffu + lsb;
  return (unsigned short)(u >> 16);
}
static __device__ __forceinline__ unsigned short f2bfv(float f) {
  __hip_bfloat16 h = __float2bfloat16(f);
  return __builtin_bit_cast(unsigned short, h);
}
static __device__ __forceinline__ bf16x8 cvt8(float4 u, float4 w, float sc) {
  bf16x8 o;
  o[0] = (short)f2bfv(u.x * sc); o[1] = (short)f2bfv(u.y * sc);
  o[2] = (short)f2bfv(u.z * sc); o[3] = (short)f2bfv(u.w * sc);
  o[4] = (short)f2bfv(w.x * sc); o[5] = (short)f2bfv(w.y * sc);
  o[6] = (short)f2bfv(w.z * sc); o[7] = (short)f2bfv(w.w * sc);
  return o;
}

// ---------------- prep ----------------
// [0,144):      Wl & Wl1 -> row-major transposes (LDS tiles; gload_lds sources)
// [144,6288):   adj rowsum -> rinv[row]  (no adj rewrite; bg scales in staging)
#define P_WT 144
#define P_RS 6144

__global__ __launch_bounds__(256) void prep(const float* __restrict__ adj,
                                            const float* __restrict__ Wl,
                                            const float* __restrict__ Wl1,
                                            float* __restrict__ rinv,
                                            unsigned short* __restrict__ WlT,
                                            unsigned short* __restrict__ Wl1T) {
  __shared__ float tile[64][65];
  const int bid = blockIdx.x;
  if (bid < P_WT) {
    const int tr = bid / 12, tc = bid % 12;
    const int c = threadIdx.x & 63, r0 = threadIdx.x >> 6;
    const float* srcs[2] = {Wl, Wl1};
    unsigned short* dsts[2] = {WlT, Wl1T};
    #pragma unroll
    for (int m = 0; m < 2; ++m) {
      const float* src = srcs[m];
      #pragma unroll
      for (int i = 0; i < 16; ++i) {
        int r = r0 + i * 4;
        tile[r][c] = src[(size_t)(tr * 64 + r) * DD + tc * 64 + c];
      }
      __syncthreads();
      unsigned short* dst = dsts[m];
      #pragma unroll
      for (int i = 0; i < 16; ++i) {
        int r2 = r0 + i * 4;
        dst[(size_t)(tc * 64 + r2) * DD + tr * 64 + c] = f2bf(tile[c][r2]);
      }
      __syncthreads();
    }
  } else {
    const int rb = bid - P_WT;
    const int wid = threadIdx.x >> 6, lane = threadIdx.x & 63;
    const int row = rb * 4 + wid;
    const float4* a = reinterpret_cast<const float4*>(adj + (size_t)row * DD);
    float4 v[3];
    float s = 0.f;
    #pragma unroll
    for (int i = 0; i < 3; ++i) {
      v[i] = a[i * 64 + lane];
      s += (v[i].x + v[i].y) + (v[i].z + v[i].w);
    }
    #pragma unroll
    for (int off = 32; off; off >>= 1) s += __shfl_down(s, off);
    if (lane == 0) rinv[row] = (s == 0.f) ? 0.f : 1.f / s;
  }
}

// ----- gemm_e1 (R20 verbatim body): A = fp32 X reg-staged, B via gload_lds.
// Epilogue: e1T ROW-MAJOR [b][d][m] (bg's gload_lds B source). -----
__global__ __launch_bounds__(256, 2) void gemm_e1(
    const float* __restrict__ X,
    const unsigned short* __restrict__ W1T,
    unsigned short* __restrict__ e1T)
{
  __shared__ char smem[2 * BUFSZ];
  constexpr int NT = 24;
  const int tid = threadIdx.x, lane = tid & 63;
  const int wid = tid >> 6;
  const int wr = wid >> 1, wc = wid & 1;

  const int logical = (blockIdx.x & 7) * 64 + (blockIdx.x >> 3);
  const int mt = logical >> 2, nt = logical & 3;
  const int b = mt >> 2;
  const float* Ag = X + (size_t)mt * BM * DD;
  const unsigned short* Bg = W1T + (size_t)nt * BN_T * DD;

  const int r_in = lane >> 2;
  const int s_in = lane & 3;

  float4 aR[3][2];
  auto issueA = [&](int s) {
    int kk = s < NT ? s : 0;
    #pragma unroll
    for (int i = 0; i < 3; ++i) {
      int row = (wid * 3 + i) * 16 + r_in;
      int slot = s_in ^ ((row >> 1) & 3);
      const float4* p = reinterpret_cast<const float4*>(
          Ag + (size_t)row * DD + kk * BK + slot * 8);
      aR[i][0] = p[0];
      aR[i][1] = p[1];
    }
  };
  auto writeA = [&](int s) {
    const int buf = (s & 1) * BUFSZ;
    #pragma unroll
    for (int i = 0; i < 3; ++i)
      *reinterpret_cast<bf16x8*>(smem + buf + (wid * 3 + i) * 1024 + lane * 16) =
          cvt8(aR[i][0], aR[i][1], 1.0f);
  };
  auto issueB = [&](int s) {
    int kk = s < NT ? s : 0;
    const int buf = (s & 1) * BUFSZ + ABUF;
    #pragma unroll
    for (int i = 0; i < 3; ++i) {
      int c = wid * 3 + i;
      int row = c * 16 + r_in;
      int slot = s_in ^ ((row >> 1) & 3);
      const unsigned short* src = Bg + (size_t)row * DD + kk * BK + slot * 8;
      __builtin_amdgcn_global_load_lds(
          (const __attribute__((address_space(1))) void*)src,
          (__attribute__((address_space(3))) void*)(smem + buf + c * 1024),
          16, 0, 0);
    }
  };

  const int ks = lane >> 4;
  auto frag = [&](int off, int row) -> bf16x8 {
    int slot = ks ^ ((row >> 1) & 3);
    return *reinterpret_cast<const bf16x8*>(smem + off + row * 64 + slot * 16);
  };

  f32x4 acc[6][6] = {};
  const int arow = wr * 96 + (lane & 15);
  const int brow = wc * 96 + (lane & 15);

  issueA(0);
  asm volatile("s_waitcnt vmcnt(0)" ::: "memory");
  writeA(0);
  issueB(0);
  issueA(1);
  asm volatile("s_waitcnt lgkmcnt(0)" ::: "memory");
  __builtin_amdgcn_s_barrier();

  for (int t = 0; t < NT; ++t) {
    asm volatile("s_waitcnt vmcnt(6)" ::: "memory");   // retire B(t); A(t+1) stays
    __builtin_amdgcn_s_barrier();
    issueB(t + 1);

    const int bufA = (t & 1) * BUFSZ;
    const int bufB = bufA + ABUF;
    bf16x8 a[6], bg[6];
    #pragma unroll
    for (int i = 0; i < 6; ++i) a[i] = frag(bufA, arow + i * 16);
    #pragma unroll
    for (int i = 0; i < 6; ++i) bg[i] = frag(bufB, brow + i * 16);

    __builtin_amdgcn_s_setprio(1);
    #pragma unroll
    for (int ni = 0; ni < 6; ++ni)
      #pragma unroll
      for (int mi = 0; mi < 6; ++mi)
        acc[mi][ni] = __builtin_amdgcn_mfma_f32_16x16x32_bf16(a[mi], bg[ni], acc[mi][ni], 0, 0, 0);
    __builtin_amdgcn_s_setprio(0);

    asm volatile("s_waitcnt vmcnt(3)" ::: "memory");   // retire A-fp32(t+1)
    writeA(t + 1);
    issueA(t + 2);
    asm volatile("s_waitcnt lgkmcnt(0)" ::: "memory");
  }

  // epilogue: e1T row-major [b][d][m] (transposed store, ushort4 over m)
  unsigned short* ob = e1T + (size_t)b * BE;
  const int m0 = (mt & 3) * BM + wr * 96 + (lane >> 4) * 4;
  const int l15 = lane & 15;
  #pragma unroll
  for (int mi = 0; mi < 6; ++mi)
    #pragma unroll
    for (int ni = 0; ni < 6; ++ni) {
      int m = m0 + mi * 16;
      int d = nt * BN_T + wc * 96 + ni * 16 + l15;
      f32x4 v = acc[mi][ni];
      ushort4 o;
      o.x = f2bf(v[0]); o.y = f2bf(v[1]); o.z = f2bf(v[2]); o.w = f2bf(v[3]);
      *reinterpret_cast<ushort4*>(ob + (size_t)d * DD + m) = o;
    }
}

// ----- gemm_bg: out = leaky( adjn@e1 + X@Wl ), 48 tiles.
// SAME counted schedule as gemm_e1 (reg-A + gload-B, the proven pairing):
// A = fp32 reg-staged (adj*rinv for t<24, X for t>=24);
// B via gload_lds (e1T row-major for t<24, WlT row-major for t>=24). -----
__global__ __launch_bounds__(256, 2) void gemm_bg(
    const float* __restrict__ adj,
    const float* __restrict__ X,
    const float* __restrict__ rinv,
    const unsigned short* __restrict__ e1T,
    const unsigned short* __restrict__ WlT,
    float* __restrict__ out)
{
  __shared__ char smem[2 * BUFSZ];
  constexpr int NT = 48;
  const int tid = threadIdx.x, lane = tid & 63;
  const int wid = tid >> 6;
  const int wr = wid >> 1, wc = wid & 1;

  const int logical = (blockIdx.x & 7) * 64 + (blockIdx.x >> 3);
  const int b = logical >> 4;
  const int r = logical & 15;
  const int mt = r >> 2, nt = r & 3;
  const size_t bo = (size_t)b * BE;
  const float* A0 = adj + bo + (size_t)mt * BM * DD;              // fp32 adj panel
  const float* A1 = X + (size_t)(b * 768 + mt * BM) * DD;         // fp32 X panel
  const unsigned short* Bg0 = e1T + bo + (size_t)nt * BN_T * DD;  // row-major [d][m]
  const unsigned short* Bg1 = WlT + (size_t)nt * BN_T * DD;       // row-major [e][d]

  const int r_in = lane >> 2;
  const int s_in = lane & 3;

  float rinv3[3];
  #pragma unroll
  for (int i = 0; i < 3; ++i)
    rinv3[i] = rinv[b * 768 + mt * BM + (wid * 3 + i) * 16 + r_in];

  float4 aR[3][2];
  auto issueA = [&](int s) {
    int sc = s < NT ? s : 0;
    const float* base = (sc >= 24) ? A1 : A0;
    int kk = (sc >= 24) ? sc - 24 : sc;
    #pragma unroll
    for (int i = 0; i < 3; ++i) {
      int row = (wid * 3 + i) * 16 + r_in;
      int slot = s_in ^ ((row >> 1) & 3);
      const float4* p = reinterpret_cast<const float4*>(
          base + (size_t)row * DD + kk * BK + slot * 8);
      aR[i][0] = p[0];
      aR[i][1] = p[1];
    }
  };
  auto writeA = [&](int s) {
    int sc = s < NT ? s : 0;
    const bool isAdj = sc < 24;
    const int buf = (s & 1) * BUFSZ;
    #pragma unroll
    for (int i = 0; i < 3; ++i) {
      float scl = isAdj ? rinv3[i] : 1.0f;
      *reinterpret_cast<bf16x8*>(smem + buf + (wid * 3 + i) * 1024 + lane * 16) =
          cvt8(aR[i][0], aR[i][1], scl);
    }
  };
  auto issueB = [&](int s) {
    int sc = s < NT ? s : 0;
    const unsigned short* base = (sc >= 24) ? Bg1 : Bg0;
    int kk = (sc >= 24) ? sc - 24 : sc;
    const int buf = (s & 1) * BUFSZ + ABUF;
    #pragma unroll
    for (int i = 0; i < 3; ++i) {
      int c = wid * 3 + i;
      int row = c * 16 + r_in;
      int slot = s_in ^ ((row >> 1) & 3);
      const unsigned short* src = base + (size_t)row * DD + kk * BK + slot * 8;
      __builtin_amdgcn_global_load_lds(
          (const __attribute__((address_space(1))) void*)src,
          (__attribute__((address_space(3))) void*)(smem + buf + c * 1024),
          16, 0, 0);
    }
  };

  const int ks = lane >> 4;
  auto frag = [&](int off, int row) -> bf16x8 {
    int slot = ks ^ ((row >> 1) & 3);
    return *reinterpret_cast<const bf16x8*>(smem + off + row * 64 + slot * 16);
  };

  f32x4 acc[6][6] = {};
  const int arow = wr * 96 + (lane & 15);
  const int brow = wc * 96 + (lane & 15);

  issueA(0);
  asm volatile("s_waitcnt vmcnt(0)" ::: "memory");
  writeA(0);
  issueB(0);
  issueA(1);
  asm volatile("s_waitcnt lgkmcnt(0)" ::: "memory");
  __builtin_amdgcn_s_barrier();

  for (int t = 0; t < NT; ++t) {
    asm volatile("s_waitcnt vmcnt(6)" ::: "memory");   // retire B(t); A(t+1) stays
    __builtin_amdgcn_s_barrier();
    issueB(t + 1);

    const int bufA = (t & 1) * BUFSZ;
    const int bufB = bufA + ABUF;
    bf16x8 a[6], bg[6];
    #pragma unroll
    for (int i = 0; i < 6; ++i) a[i] = frag(bufA, arow + i * 16);
    #pragma unroll
    for (int i = 0; i < 6; ++i) bg[i] = frag(bufB, brow + i * 16);

    __builtin_amdgcn_s_setprio(1);
    #pragma unroll
    for (int ni = 0; ni < 6; ++ni)
      #pragma unroll
      for (int mi = 0; mi < 6; ++mi)
        acc[mi][ni] = __builtin_amdgcn_mfma_f32_16x16x32_bf16(a[mi], bg[ni], acc[mi][ni], 0, 0, 0);
    __builtin_amdgcn_s_setprio(0);

    asm volatile("s_waitcnt vmcnt(3)" ::: "memory");   // retire A-fp32(t+1)
    writeA(t + 1);
    issueA(t + 2);
    asm volatile("s_waitcnt lgkmcnt(0)" ::: "memory");
  }

  float* ob = out + bo;
  const int m0 = mt * BM + wr * 96 + (lane >> 4) * 4;
  const int l15 = lane & 15;
  #pragma unroll
  for (int mi = 0; mi < 6; ++mi)
    #pragma unroll
    for (int ni = 0; ni < 6; ++ni) {
      int m = m0 + mi * 16;
      int n = nt * BN_T + wc * 96 + ni * 16 + l15;
      f32x4 v = acc[mi][ni];
      #pragma unroll
      for (int j = 0; j < 4; ++j) {
        float x = v[j];
        ob[(size_t)(m + j) * DD + n] = x > 0.f ? x : 0.01f * x;
      }
    }
}

// ---------------- launch ----------------

extern "C" void kernel_launch(void* const* d_in, const int* in_sizes, int n_in,
                              void* d_out, int out_size, void* d_ws, size_t ws_size,
                              hipStream_t stream) {
  const float* X   = (const float*)d_in[0];
  const float* adj = (const float*)d_in[1];
  const float* Wl  = (const float*)d_in[2];
  const float* Wl1 = (const float*)d_in[3];
  float* out = (float*)d_out;

  char* ws = (char*)d_ws;
  const size_t SZ = (size_t)BN_ROWS * DD * 2;     // 37,748,736 bytes (e1T)
  unsigned short* e1T  = (unsigned short*)(ws);                       // row-major [b][d][m]
  unsigned short* WlT  = (unsigned short*)(ws + SZ);                  // row-major [e][d]
  unsigned short* Wl1T = (unsigned short*)(ws + SZ + (size_t)BE * 2); // row-major [e][d]
  float* rinv          = (float*)(ws + SZ + 2 * (size_t)BE * 2);

  prep<<<P_WT + P_RS, 256, 0, stream>>>(adj, Wl, Wl1, rinv, WlT, Wl1T);
  gemm_e1<<<512, 256, 0, stream>>>(X, Wl1T, e1T);
  gemm_bg<<<512, 256, 0, stream>>>(adj, X, rinv, e1T, WlT, out);
}

// Round 23
// 133.896 us; speedup vs baseline: 1.2565x; 1.1361x over previous
//
#include <hip/hip_runtime.h>
#include <hip/hip_bf16.h>
#include <cstdint>
#include <cstddef>

// Problem constants: B=32, N=768, D=768
#define BN_ROWS 24576
#define DD 768
#define BE (768*768)
#define BM 192
#define BN_T 192
#define BK 32
#define ABUF 12288
#define BUFSZ 24576

typedef __attribute__((ext_vector_type(8))) short bf16x8;
typedef __attribute__((ext_vector_type(4))) float f32x4;
typedef __attribute__((ext_vector_type(8))) unsigned short u16x8;

static __device__ __forceinline__ unsigned short f2bf(float f) {
  unsigned int u = __builtin_bit_cast(unsigned int, f);
  unsigned int lsb = (u >> 16) & 1u;
  u += 0x7fffu + lsb;
  return (unsigned short)(u >> 16);
}

static __device__ __forceinline__ unsigned short f2bfv(float f) {
  __hip_bfloat16 h = __float2bfloat16(f);
  return __builtin_bit_cast(unsigned short, h);
}

static __device__ __forceinline__ bf16x8 cvt8(float4 u, float4 w, float sc) {
  bf16x8 o;
  o[0] = (short)f2bfv(u.x * sc); o[1] = (short)f2bfv(u.y * sc);
  o[2] = (short)f2bfv(u.z * sc); o[3] = (short)f2bfv(u.w * sc);
  o[4] = (short)f2bfv(w.x * sc); o[5] = (short)f2bfv(w.y * sc);
  o[6] = (short)f2bfv(w.z * sc); o[7] = (short)f2bfv(w.w * sc);
  return o;
}

// ---------------- prep: weight transposes + adj rowsum ----------------
// [0,144):    Wl1 -> Wl1T row-major transpose (gemm_e1 B, gload_lds source)
// [144,432):  Wl  -> WlT frag-linear (gemm_bg B, direct-to-reg source)
// [432,6576): adj rowsum -> rinv[row] (NO adj write; GEMM scales in staging)

#define PREP_WT 144
#define PREP_FL 288
#define PREP_RS 6144

__global__ __launch_bounds__(256) void prep(const float* __restrict__ adj,
                                            const float* __restrict__ Wl,
                                            const float* __restrict__ Wl1,
                                            float* __restrict__ rinv,
                                            unsigned short* __restrict__ WlT,
                                            unsigned short* __restrict__ Wl1T) {
  __shared__ float tile[64][65];
  const int bid = blockIdx.x;
  if (bid < PREP_WT) {
    const int tr = bid / 12, tc = bid % 12;
    const int c = threadIdx.x & 63, r0 = threadIdx.x >> 6;
    #pragma unroll
    for (int i = 0; i < 16; ++i) {
      int r = r0 + i * 4;
      tile[r][c] = Wl1[(size_t)(tr * 64 + r) * DD + tc * 64 + c];
    }
    __syncthreads();
    #pragma unroll
    for (int i = 0; i < 16; ++i) {
      int r2 = r0 + i * 4;
      Wl1T[(size_t)(tc * 64 + r2) * DD + tr * 64 + c] = f2bf(tile[c][r2]);
    }
  } else if (bid < PREP_WT + PREP_FL) {
    const int b2 = bid - PREP_WT;
    const int wg = b2 * 4 + (threadIdx.x >> 6);   // 0..1151
    const int lane = threadIdx.x & 63;
    const int d0 = (wg % 96) * 8;
    const int e = (wg / 96) * 64 + lane;
    u16x8 o;
    #pragma unroll
    for (int j = 0; j < 8; ++j)
      o[j] = f2bf(Wl[(size_t)(d0 + j) * DD + e]);
    const int base = ((e >> 4) * 24 + (d0 >> 5)) * 512
                   + ((e & 15) + (((d0 >> 3) & 3) << 4)) * 8;
    *reinterpret_cast<u16x8*>(WlT + base) = o;
  } else {
    const int rb = bid - (PREP_WT + PREP_FL);
    const int wid = threadIdx.x >> 6, lane = threadIdx.x & 63;
    const int row = rb * 4 + wid;
    const float4* a = reinterpret_cast<const float4*>(adj + (size_t)row * DD);
    float4 v[3];
    float s = 0.f;
    #pragma unroll
    for (int i = 0; i < 3; ++i) {
      v[i] = a[i * 64 + lane];
      s += (v[i].x + v[i].y) + (v[i].z + v[i].w);
    }
    #pragma unroll
    for (int off = 32; off; off >>= 1) s += __shfl_down(s, off);
    if (lane == 0) rinv[row] = (s == 0.f) ? 0.f : 1.f / s;
  }
}

// ----- gemm_e1: 192x192 dbuf, A reg-staged from fp32 X, B via gload_lds -----
// Per tile t: { vmcnt(6)[B(t) landed; A-fp32(t+1) in flight]; barrier;
//   issueB(t+1); ds_read frags(t); 36 MFMA; vmcnt(3)[A-fp32(t+1) landed];
//   cvt+ds_write A(t+1)->buf[(t+1)&1]; issueA(t+2); lgkm(0) }.
// All waits counted; parity separates writes from concurrent readers.
// Epilogue writes e1T FRAG-LINEAR (gemm_bg B source).
__global__ __launch_bounds__(256, 2) void gemm_e1(
    const float* __restrict__ X,
    const unsigned short* __restrict__ W1T,
    unsigned short* __restrict__ e1T)
{
  __shared__ char smem[2 * BUFSZ];
  constexpr int NT = 24;
  const int tid = threadIdx.x, lane = tid & 63;
  const int wid = tid >> 6;
  const int wr = wid >> 1, wc = wid & 1;

  const int logical = (blockIdx.x & 7) * 64 + (blockIdx.x >> 3);
  const int mt = logical >> 2, nt = logical & 3;
  const int b = mt >> 2;
  const float* Ag = X + (size_t)mt * BM * DD;
  const unsigned short* Bg = W1T + (size_t)nt * BN_T * DD;

  const int r_in = lane >> 2;
  const int s_in = lane & 3;

  float4 aR[3][2];
  auto issueA = [&](int s) {
    int kk = s < NT ? s : 0;
    #pragma unroll
    for (int i = 0; i < 3; ++i) {
      int row = (wid * 3 + i) * 16 + r_in;
      int slot = s_in ^ ((row >> 1) & 3);
      const float4* p = reinterpret_cast<const float4*>(
          Ag + (size_t)row * DD + kk * BK + slot * 8);
      aR[i][0] = p[0];
      aR[i][1] = p[1];
    }
  };
  auto writeA = [&](int s) {
    const int buf = (s & 1) * BUFSZ;
    #pragma unroll
    for (int i = 0; i < 3; ++i)
      *reinterpret_cast<bf16x8*>(smem + buf + (wid * 3 + i) * 1024 + lane * 16) =
          cvt8(aR[i][0], aR[i][1], 1.0f);
  };
  auto issueB = [&](int s) {
    int kk = s < NT ? s : 0;
    const int buf = (s & 1) * BUFSZ + ABUF;
    #pragma unroll
    for (int i = 0; i < 3; ++i) {
      int c = wid * 3 + i;
      int row = c * 16 + r_in;
      int slot = s_in ^ ((row >> 1) & 3);
      const unsigned short* src = Bg + (size_t)row * DD + kk * BK + slot * 8;
      __builtin_amdgcn_global_load_lds(
          (const __attribute__((address_space(1))) void*)src,
          (__attribute__((address_space(3))) void*)(smem + buf + c * 1024),
          16, 0, 0);
    }
  };

  const int ks = lane >> 4;
  auto frag = [&](int off, int row) -> bf16x8 {
    int slot = ks ^ ((row >> 1) & 3);
    return *reinterpret_cast<const bf16x8*>(smem + off + row * 64 + slot * 16);
  };

  f32x4 acc[6][6] = {};
  const int arow = wr * 96 + (lane & 15);
  const int brow = wc * 96 + (lane & 15);

  // prologue: in-flight at loop entry = B(0)[3, oldest] + A(1)[6]
  issueA(0);
  asm volatile("s_waitcnt vmcnt(0)" ::: "memory");
  writeA(0);
  issueB(0);
  issueA(1);
  asm volatile("s_waitcnt lgkmcnt(0)" ::: "memory");
  __builtin_amdgcn_s_barrier();

  for (int t = 0; t < NT; ++t) {
    asm volatile("s_waitcnt vmcnt(6)" ::: "memory");   // retire B(t); A(t+1) stays
    __builtin_amdgcn_s_barrier();
    issueB(t + 1);                                     // -> buf[(t+1)&1].B (safe)

    const int bufA = (t & 1) * BUFSZ;
    const int bufB = bufA + ABUF;
    bf16x8 a[6], bg[6];
    #pragma unroll
    for (int i = 0; i < 6; ++i) a[i] = frag(bufA, arow + i * 16);
    #pragma unroll
    for (int i = 0; i < 6; ++i) bg[i] = frag(bufB, brow + i * 16);

    __builtin_amdgcn_s_setprio(1);
    #pragma unroll
    for (int ni = 0; ni < 6; ++ni)
      #pragma unroll
      for (int mi = 0; mi < 6; ++mi)
        acc[mi][ni] = __builtin_amdgcn_mfma_f32_16x16x32_bf16(a[mi], bg[ni], acc[mi][ni], 0, 0, 0);
    __builtin_amdgcn_s_setprio(0);

    asm volatile("s_waitcnt vmcnt(3)" ::: "memory");   // retire A-fp32(t+1)
    writeA(t + 1);                                     // -> buf[(t+1)&1].A (safe)
    issueA(t + 2);                                     // invariant restored
    asm volatile("s_waitcnt lgkmcnt(0)" ::: "memory"); // ds_writes visible pre-barrier
  }

  // epilogue: frag-linear e1T (col=d, k=m)
  unsigned short* ob = e1T + (size_t)b * BE;
  const int m0 = (mt & 3) * BM + wr * 96 + (lane >> 4) * 4;
  const int l15 = lane & 15;
  #pragma unroll
  for (int mi = 0; mi < 6; ++mi)
    #pragma unroll
    for (int ni = 0; ni < 6; ++ni) {
      int m = m0 + mi * 16;
      int cb = nt * 12 + wc * 6 + ni;
      int fa = (cb * 24 + (m >> 5)) * 512
             + (l15 + (((m >> 3) & 3) << 4)) * 8 + (m & 7);
      f32x4 v = acc[mi][ni];
      ushort4 o;
      o.x = f2bf(v[0]); o.y = f2bf(v[1]); o.z = f2bf(v[2]); o.w = f2bf(v[3]);
      *reinterpret_cast<ushort4*>(ob + fa) = o;
    }
}

// ----- gemm_bg: A reg-staged from fp32 (adj*rinv | X), B direct-to-reg -----
// out = leaky( adjn@e1 + X@Wl ), fused 48-tile K-loop. Per half-iter:
// { loadB(t+1)->other regs; ds_read a; 36 MFMA (compiler waits this-B);
//   vmcnt(6)[A-fp32(t+1) retired, B(t+1) in flight]; cvt*scale+ds_write
//   A(t+1)->bufW; issueA(t+2); lgkm(0); barrier }.
__global__ __launch_bounds__(256, 2) void gemm_bg(
    const float* __restrict__ adj,
    const float* __restrict__ X,
    const float* __restrict__ rinv,
    const unsigned short* __restrict__ e1T,
    const unsigned short* __restrict__ WlT,
    float* __restrict__ out)
{
  __shared__ char smem[2 * 12288];
  constexpr int NT = 48;
  const int tid = threadIdx.x, lane = tid & 63;
  const int wid = tid >> 6;
  const int wr = wid >> 1, wc = wid & 1;

  const int logical = (blockIdx.x & 7) * 64 + (blockIdx.x >> 3);
  const int b = logical >> 4;
  const int r = logical & 15;
  const int mt = r >> 2, nt = r & 3;
  const size_t bo = (size_t)b * BE;
  const float* A0 = adj + bo + (size_t)mt * BM * DD;          // fp32 adj panel
  const float* A1 = X + (size_t)(b * 768 + mt * BM) * DD;     // fp32 X panel
  const unsigned short* B0 = e1T + bo;                        // frag-linear
  const unsigned short* B1 = WlT;                             // frag-linear

  const int r_in = lane >> 2;
  const int s_in = lane & 3;
  const int colblk0 = nt * 12 + wc * 6;

  float rinv3[3];
  #pragma unroll
  for (int i = 0; i < 3; ++i)
    rinv3[i] = rinv[b * 768 + mt * BM + (wid * 3 + i) * 16 + r_in];

  float4 aR[3][2];
  auto issueA = [&](int s) {
    int sc = s < NT ? s : 0;
    const float* base = (sc >= 24) ? A1 : A0;
    int kk = (sc >= 24) ? sc - 24 : sc;
    #pragma unroll
    for (int i = 0; i < 3; ++i) {
      int row = (wid * 3 + i) * 16 + r_in;
      int slot = s_in ^ ((row >> 1) & 3);
      const float4* p = reinterpret_cast<const float4*>(
          base + (size_t)row * DD + kk * BK + slot * 8);
      aR[i][0] = p[0];
      aR[i][1] = p[1];
    }
  };
  auto writeA = [&](int s) {
    int sc = s < NT ? s : 0;
    const bool isAdj = sc < 24;
    const int buf = (s & 1) * 12288;
    #pragma unroll
    for (int i = 0; i < 3; ++i) {
      float scl = isAdj ? rinv3[i] : 1.0f;
      *reinterpret_cast<bf16x8*>(smem + buf + (wid * 3 + i) * 1024 + lane * 16) =
          cvt8(aR[i][0], aR[i][1], scl);
    }
  };
  auto loadB = [&](int s, bf16x8* dst) {
    int sc = s < NT ? s : 0;
    const unsigned short* base = (sc >= 24) ? B1 : B0;
    int kk = (sc >= 24) ? sc - 24 : sc;
    #pragma unroll
    for (int ni = 0; ni < 6; ++ni)
      dst[ni] = *reinterpret_cast<const bf16x8*>(
          base + ((colblk0 + ni) * 24 + kk) * 512 + lane * 8);
  };

  const int ks = lane >> 4;
  auto rdA = [&](int off, int row) -> bf16x8 {
    int slot = ks ^ ((row >> 1) & 3);
    return *reinterpret_cast<const bf16x8*>(smem + off + row * 64 + slot * 16);
  };

  f32x4 acc[6][6] = {};
  const int arow = wr * 96 + (lane & 15);
  bf16x8 bA[6], bB[6];

  auto body = [&](int bufo, bf16x8* bfr) {
    #pragma unroll
    for (int mh = 0; mh < 2; ++mh) {
      bf16x8 a[3];
      #pragma unroll
      for (int i = 0; i < 3; ++i) a[i] = rdA(bufo, arow + mh * 48 + i * 16);
      __builtin_amdgcn_s_setprio(1);
      #pragma unroll
      for (int mi = 0; mi < 3; ++mi)
        #pragma unroll
        for (int ni = 0; ni < 6; ++ni)
          acc[mh * 3 + mi][ni] = __builtin_amdgcn_mfma_f32_16x16x32_bf16(
              a[mi], bfr[ni], acc[mh * 3 + mi][ni], 0, 0, 0);
      __builtin_amdgcn_s_setprio(0);
    }
  };

  // prologue
  issueA(0);
  asm volatile("s_waitcnt vmcnt(0)" ::: "memory");
  writeA(0);
  loadB(0, bA);
  issueA(1);
  asm volatile("s_waitcnt lgkmcnt(0)" ::: "memory");
  __builtin_amdgcn_s_barrier();

  for (int t = 0; t < NT; t += 2) {
    // half t (even): read buf0 with bA; write buf1
    loadB(t + 1, bB);
    body(0, bA);
    asm volatile("s_waitcnt vmcnt(6)" ::: "memory");   // A-fp32(t+1) retired
    writeA(t + 1);
    issueA(t + 2);
    asm volatile("s_waitcnt lgkmcnt(0)" ::: "memory");
    __builtin_amdgcn_s_barrier();

    // half t+1 (odd): read buf1 with bB; write buf0
    loadB(t + 2, bA);
    body(12288, bB);
    asm volatile("s_waitcnt vmcnt(6)" ::: "memory");
    writeA(t + 2);
    issueA(t + 3);
    asm volatile("s_waitcnt lgkmcnt(0)" ::: "memory");
    __builtin_amdgcn_s_barrier();
  }

  float* ob = out + bo;
  const int m0 = mt * BM + wr * 96 + (lane >> 4) * 4;
  const int l15 = lane & 15;
  #pragma unroll
  for (int mi = 0; mi < 6; ++mi)
    #pragma unroll
    for (int ni = 0; ni < 6; ++ni) {
      int m = m0 + mi * 16;
      int n = nt * BN_T + wc * 96 + ni * 16 + l15;
      f32x4 v = acc[mi][ni];
      #pragma unroll
      for (int j = 0; j < 4; ++j) {
        float x = v[j];
        ob[(size_t)(m + j) * DD + n] = x > 0.f ? x : 0.01f * x;
      }
    }
}

// ---------------- launch ----------------

extern "C" void kernel_launch(void* const* d_in, const int* in_sizes, int n_in,
                              void* d_out, int out_size, void* d_ws, size_t ws_size,
                              hipStream_t stream) {
  const float* X   = (const float*)d_in[0];
  const float* adj = (const float*)d_in[1];
  const float* Wl  = (const float*)d_in[2];
  const float* Wl1 = (const float*)d_in[3];
  float* out = (float*)d_out;

  char* ws = (char*)d_ws;
  const size_t SZ = (size_t)BN_ROWS * DD * 2;     // 37,748,736 bytes (e1T)
  unsigned short* e1T  = (unsigned short*)(ws);                    // frag-linear
  unsigned short* WlT  = (unsigned short*)(ws + SZ);               // frag-linear
  unsigned short* Wl1T = (unsigned short*)(ws + SZ + (size_t)BE * 2); // row-major
  float* rinv          = (float*)(ws + SZ + 2 * (size_t)BE * 2);

  prep<<<PREP_WT + PREP_FL + PREP_RS, 256, 0, stream>>>(adj, Wl, Wl1, rinv, WlT, Wl1T);
  gemm_e1<<<512, 256, 0, stream>>>(X, Wl1T, e1T);
  gemm_bg<<<512, 256, 0, stream>>>(adj, X, rinv, e1T, WlT, out);
}